// Round 1
// baseline (2324.779 us; speedup 1.0000x reference)
//
#include <hip/hip_runtime.h>

#define Bn 4
#define Hn 128
#define Wn 128
#define Cn 17
#define PCn 51
#define WIDTHn 128
#define STEPSn 48
#define NPIX (Bn*Hn*Wn)

// Kernel 1: compute unmasked new state for all C channels.
// Reads neighborhoods of `state` (previous masked state), writes unmasked
// result to outU (= dev_path[s]) and the channel-3 plane to ch3plane (ws).
__global__ __launch_bounds__(256) void nca_update(
    const float* __restrict__ state, const float* __restrict__ rplane,
    const float* __restrict__ W1, const float* __restrict__ b1,
    const float* __restrict__ W2, const float* __restrict__ b2,
    float* __restrict__ outU, float* __restrict__ ch3plane)
{
  int tid = blockIdx.x * blockDim.x + threadIdx.x;
  int x = tid & (Wn - 1);
  int y = (tid >> 7) & (Hn - 1);
  int b = tid >> 14;

  const float* sb = state + (size_t)b * Cn * Hn * Wn;
  float ang = sb[(16 * Hn + y) * Wn + x];
  float ca = cosf(ang), sa = sinf(ang);

  float p[PCn];
  bool ym = y > 0, yp = y < Hn - 1, xm = x > 0, xp = x < Wn - 1;
  int r0 = (y - 1) * Wn + x, r1 = y * Wn + x, r2 = (y + 1) * Wn + x;
#pragma unroll
  for (int c = 0; c < Cn; ++c) {
    const float* sc = sb + c * Hn * Wn;
    float n00 = 0.f, n01 = 0.f, n02 = 0.f, n10 = 0.f, n11, n12 = 0.f,
          n20 = 0.f, n21 = 0.f, n22 = 0.f;
    if (ym) { if (xm) n00 = sc[r0 - 1]; n01 = sc[r0]; if (xp) n02 = sc[r0 + 1]; }
    if (xm) n10 = sc[r1 - 1];
    n11 = sc[r1];
    if (xp) n12 = sc[r1 + 1];
    if (yp) { if (xm) n20 = sc[r2 - 1]; n21 = sc[r2]; if (xp) n22 = sc[r2 + 1]; }
    // cross-correlation with SOBEL_X and SOBEL_Y (= SOBEL_X^T), /8
    float gx = (n02 - n00 + 2.f * (n12 - n10) + n22 - n20) * 0.125f;
    float gy = (n20 - n00 + 2.f * (n21 - n01) + n22 - n02) * 0.125f;
    p[c] = n11;
    p[17 + c] = ca * gx + sa * gy;        // px
    p[34 + c] = ca * gy - sa * gx;        // py
  }

  float d[Cn];
#pragma unroll
  for (int j = 0; j < Cn; ++j) d[j] = b2[j];
  for (int o = 0; o < WIDTHn; ++o) {
    float acc = b1[o];
    const float* w1r = W1 + o * PCn;
#pragma unroll
    for (int c = 0; c < PCn; ++c) acc = fmaf(w1r[c], p[c], acc);
    float hr = fmaxf(acc, 0.f);
#pragma unroll
    for (int j = 0; j < Cn; ++j) d[j] = fmaf(W2[j * WIDTHn + o], hr, d[j]);
  }

  float upd = (rplane[(b * Hn + y) * Wn + x] < 0.5f) ? 1.f : 0.f;
#pragma unroll
  for (int c = 0; c < Cn; ++c) {
    float nv = fmaf(d[c], upd, p[c]);
    outU[(((size_t)b * Cn + c) * Hn + y) * Wn + x] = nv;
  }
  ch3plane[(b * Hn + y) * Wn + x] = fmaf(d[3], upd, p[3]);
}

// Kernel 2: alive gating. premax from old state's ch3 (untouched buffer),
// postmax from the ch3 plane in ws (so the in-place rewrite of newState is
// race-free: all cross-pixel reads come from other buffers).
__global__ __launch_bounds__(256) void nca_alive(
    const float* __restrict__ oldState, const float* __restrict__ ch3plane,
    float* __restrict__ newState)
{
  int tid = blockIdx.x * blockDim.x + threadIdx.x;
  int x = tid & (Wn - 1);
  int y = (tid >> 7) & (Hn - 1);
  int b = tid >> 14;
  const float* o3 = oldState + ((size_t)b * Cn + 3) * Hn * Wn;
  const float* p3 = ch3plane + (size_t)b * Hn * Wn;
  float pre = -1e30f, post = -1e30f;
#pragma unroll
  for (int dy = -1; dy <= 1; ++dy) {
    int yy = y + dy;
    if (yy < 0 || yy >= Hn) continue;
#pragma unroll
    for (int dxx = -1; dxx <= 1; ++dxx) {
      int xx = x + dxx;
      if (xx < 0 || xx >= Wn) continue;
      pre = fmaxf(pre, o3[yy * Wn + xx]);
      post = fmaxf(post, p3[yy * Wn + xx]);
    }
  }
  float alive = (pre > 0.1f && post > 0.1f) ? 1.f : 0.f;
#pragma unroll
  for (int c = 0; c < Cn; ++c) {
    size_t i = (((size_t)b * Cn + c) * Hn + y) * Wn + x;
    newState[i] *= alive;
  }
}

// Final: copy channels 0..3 of the last state into output 0.
__global__ __launch_bounds__(256) void nca_final(
    const float* __restrict__ last, float* __restrict__ out4)
{
  int tid = blockIdx.x * blockDim.x + threadIdx.x; // B*4*H*W
  int x = tid & 127, y = (tid >> 7) & 127, c = (tid >> 14) & 3, b = tid >> 16;
  out4[tid] = last[(((size_t)b * Cn + c) * Hn + y) * Wn + x];
}

extern "C" void kernel_launch(void* const* d_in, const int* in_sizes, int n_in,
                              void* d_out, int out_size, void* d_ws, size_t ws_size,
                              hipStream_t stream) {
  const float* init_state = (const float*)d_in[0];
  const float* rand_all   = (const float*)d_in[1];
  const float* W1 = (const float*)d_in[2];
  const float* b1 = (const float*)d_in[3];
  const float* W2 = (const float*)d_in[4];
  const float* b2 = (const float*)d_in[5];

  float* out = (float*)d_out;
  float* final4 = out;                                   // [B,4,H,W]
  float* dev_path = out + (size_t)Bn * 4 * Hn * Wn;      // [STEPS,B,C,H,W]
  float* ch3 = (float*)d_ws;                             // [B,H,W] plane

  const size_t stateSz = (size_t)Bn * Cn * Hn * Wn;
  dim3 block(256), grid(NPIX / 256);

  for (int s = 0; s < STEPSn; ++s) {
    const float* cur = (s == 0) ? init_state
                                : (const float*)(dev_path + (size_t)(s - 1) * stateSz);
    float* nxt = dev_path + (size_t)s * stateSz;
    const float* rp = rand_all + (size_t)s * Bn * Hn * Wn;
    hipLaunchKernelGGL(nca_update, grid, block, 0, stream,
                       cur, rp, W1, b1, W2, b2, nxt, ch3);
    hipLaunchKernelGGL(nca_alive, grid, block, 0, stream, cur, ch3, nxt);
  }
  hipLaunchKernelGGL(nca_final, dim3((size_t)Bn * 4 * Hn * Wn / 256), block, 0,
                     stream, dev_path + (size_t)(STEPSn - 1) * stateSz, final4);
}

// Round 2
// 1485.162 us; speedup vs baseline: 1.5653x; 1.5653x over previous
//
#include <hip/hip_runtime.h>

#define Bn 4
#define Hn 128
#define Wn 128
#define Cn 17
#define PCn 51
#define WIDTHn 128
#define STEPSn 48
#define NPIX (Bn*Hn*Wn)
#define TPIX 64

// Update kernel: 256 threads = 64 pixels x 4 hidden-groups.
// Phase 1: cooperative sobel+rotation -> p_lds[64][51]
// Phase 2: each thread does 32 hidden units over its pixel (p cached in regs)
// Phase 3: LDS-reduce 4 partials, apply update mask, write unmasked new state.
__global__ __launch_bounds__(256, 4) void nca_update(
    const float* __restrict__ state, const float* __restrict__ rplane,
    const float* __restrict__ W1, const float* __restrict__ b1,
    const float* __restrict__ W2, const float* __restrict__ b2,
    float* __restrict__ outU, float* __restrict__ ch3plane)
{
  __shared__ float p_lds[TPIX][PCn];     // 13056 B (stride 51, odd -> conflict-free)
  __shared__ float ca_lds[TPIX], sa_lds[TPIX];
  __shared__ float dred[4][TPIX][Cn];    // 17408 B

  int tid = threadIdx.x;
  int pix = tid & 63;
  int gpix0 = blockIdx.x * TPIX;         // 64 consecutive pixels: same b, same row
  int x0 = gpix0 & (Wn - 1);
  int y  = (gpix0 >> 7) & (Hn - 1);
  int b  = gpix0 >> 14;
  const float* sb = state + (size_t)b * Cn * Hn * Wn;

  if (tid < TPIX) {
    float ang = sb[(16 * Hn + y) * Wn + x0 + tid];
    ca_lds[tid] = cosf(ang);
    sa_lds[tid] = sinf(ang);
  }
  __syncthreads();

  {
    int x = x0 + pix;
    bool ym = y > 0, yp = y < Hn - 1, xm = x > 0, xp = x < Wn - 1;
    int r0 = (y - 1) * Wn + x, r1 = y * Wn + x, r2 = (y + 1) * Wn + x;
    float ca = ca_lds[pix], sa = sa_lds[pix];
    for (int c = (tid >> 6); c < Cn; c += 4) {
      const float* sc = sb + c * Hn * Wn;
      float n00=0.f,n01=0.f,n02=0.f,n10=0.f,n11,n12=0.f,n20=0.f,n21=0.f,n22=0.f;
      if (ym) { if (xm) n00 = sc[r0-1]; n01 = sc[r0]; if (xp) n02 = sc[r0+1]; }
      if (xm) n10 = sc[r1-1];
      n11 = sc[r1];
      if (xp) n12 = sc[r1+1];
      if (yp) { if (xm) n20 = sc[r2-1]; n21 = sc[r2]; if (xp) n22 = sc[r2+1]; }
      float gx = (n02-n00 + 2.f*(n12-n10) + n22-n20) * 0.125f;
      float gy = (n20-n00 + 2.f*(n21-n01) + n22-n02) * 0.125f;
      p_lds[pix][c]      = n11;
      p_lds[pix][17 + c] = ca*gx + sa*gy;   // px
      p_lds[pix][34 + c] = ca*gy - sa*gx;   // py
    }
  }
  __syncthreads();

  {
    int t = __builtin_amdgcn_readfirstlane(tid >> 6);  // wave index -> s_loads for W1/W2
    float p[PCn];
    #pragma unroll
    for (int c = 0; c < PCn; ++c) p[c] = p_lds[pix][c];
    float d[Cn];
    #pragma unroll
    for (int j = 0; j < Cn; ++j) d[j] = 0.f;
    int o0 = t * 32;
    for (int o = o0; o < o0 + 32; ++o) {
      float acc = b1[o];
      const float* w1r = W1 + o * PCn;
      #pragma unroll
      for (int c = 0; c < PCn; ++c) acc = fmaf(w1r[c], p[c], acc);
      float hr = fmaxf(acc, 0.f);
      #pragma unroll
      for (int j = 0; j < Cn; ++j) d[j] = fmaf(W2[j * WIDTHn + o], hr, d[j]);
    }
    #pragma unroll
    for (int j = 0; j < Cn; ++j) dred[t][pix][j] = d[j];
  }
  __syncthreads();

  {
    int x = x0 + pix;
    float upd = (rplane[gpix0 + pix] < 0.5f) ? 1.f : 0.f;
    for (int c = (tid >> 6); c < Cn; c += 4) {
      float dsum = dred[0][pix][c] + dred[1][pix][c]
                 + dred[2][pix][c] + dred[3][pix][c] + b2[c];
      float nv = fmaf(dsum, upd, p_lds[pix][c]);
      outU[(((size_t)b * Cn + c) * Hn + y) * Wn + x] = nv;
      if (c == 3) ch3plane[gpix0 + pix] = nv;
    }
  }
}

// Alive gating: pre from old masked state's ch3, post from unmasked-new ch3
// plane in ws; rewrite newState in place (race-free: cross-pixel reads come
// from other buffers).
__global__ __launch_bounds__(256) void nca_alive(
    const float* __restrict__ oldState, const float* __restrict__ ch3plane,
    float* __restrict__ newState)
{
  int tid = blockIdx.x * blockDim.x + threadIdx.x;
  int x = tid & (Wn - 1);
  int y = (tid >> 7) & (Hn - 1);
  int b = tid >> 14;
  const float* o3 = oldState + ((size_t)b * Cn + 3) * Hn * Wn;
  const float* p3 = ch3plane + (size_t)b * Hn * Wn;
  float pre = -1e30f, post = -1e30f;
#pragma unroll
  for (int dy = -1; dy <= 1; ++dy) {
    int yy = y + dy;
    if (yy < 0 || yy >= Hn) continue;
#pragma unroll
    for (int dxx = -1; dxx <= 1; ++dxx) {
      int xx = x + dxx;
      if (xx < 0 || xx >= Wn) continue;
      pre = fmaxf(pre, o3[yy * Wn + xx]);
      post = fmaxf(post, p3[yy * Wn + xx]);
    }
  }
  float alive = (pre > 0.1f && post > 0.1f) ? 1.f : 0.f;
#pragma unroll
  for (int c = 0; c < Cn; ++c) {
    size_t i = (((size_t)b * Cn + c) * Hn + y) * Wn + x;
    newState[i] *= alive;
  }
}

__global__ __launch_bounds__(256) void nca_final(
    const float* __restrict__ last, float* __restrict__ out4)
{
  int tid = blockIdx.x * blockDim.x + threadIdx.x; // B*4*H*W
  int x = tid & 127, y = (tid >> 7) & 127, c = (tid >> 14) & 3, b = tid >> 16;
  out4[tid] = last[(((size_t)b * Cn + c) * Hn + y) * Wn + x];
}

extern "C" void kernel_launch(void* const* d_in, const int* in_sizes, int n_in,
                              void* d_out, int out_size, void* d_ws, size_t ws_size,
                              hipStream_t stream) {
  const float* init_state = (const float*)d_in[0];
  const float* rand_all   = (const float*)d_in[1];
  const float* W1 = (const float*)d_in[2];
  const float* b1 = (const float*)d_in[3];
  const float* W2 = (const float*)d_in[4];
  const float* b2 = (const float*)d_in[5];

  float* out = (float*)d_out;
  float* final4 = out;                                   // [B,4,H,W]
  float* dev_path = out + (size_t)Bn * 4 * Hn * Wn;      // [STEPS,B,C,H,W]
  float* ch3 = (float*)d_ws;                             // [B,H,W] plane

  const size_t stateSz = (size_t)Bn * Cn * Hn * Wn;
  dim3 block(256);
  dim3 gridU(NPIX / TPIX);   // 1024
  dim3 gridA(NPIX / 256);    // 256

  for (int s = 0; s < STEPSn; ++s) {
    const float* cur = (s == 0) ? init_state
                                : (const float*)(dev_path + (size_t)(s - 1) * stateSz);
    float* nxt = dev_path + (size_t)s * stateSz;
    const float* rp = rand_all + (size_t)s * Bn * Hn * Wn;
    hipLaunchKernelGGL(nca_update, gridU, block, 0, stream,
                       cur, rp, W1, b1, W2, b2, nxt, ch3);
    hipLaunchKernelGGL(nca_alive, gridA, block, 0, stream, cur, ch3, nxt);
  }
  hipLaunchKernelGGL(nca_final, dim3((size_t)Bn * 4 * Hn * Wn / 256), block, 0,
                     stream, dev_path + (size_t)(STEPSn - 1) * stateSz, final4);
}

// Round 3
// 728.752 us; speedup vs baseline: 3.1901x; 2.0380x over previous
//
#include <hip/hip_runtime.h>

typedef _Float16 half8 __attribute__((ext_vector_type(8)));
typedef _Float16 half4v __attribute__((ext_vector_type(4)));
typedef float f32x4v __attribute__((ext_vector_type(4)));

#define Bn 4
#define Hn 128
#define Wn 128
#define HW (Hn*Wn)
#define Cn 17
#define STEPSn 48
#define NPIX (Bn*HW)

// d_ws layout (bytes):
#define CH3_OFF   0                       // 65536 f32 = 262144 B
#define W1IMG_OFF 262144                  // 128 x 72 fp16 (K padded 51->64, row 16B-aligned)
#define W2IMG_OFF (262144 + 18432)       // 32 x 128 fp16 (rows 17..31 zero)

// One-time weight conversion to padded fp16 images.
__global__ __launch_bounds__(256) void nca_prep(
    const float* __restrict__ W1, const float* __restrict__ W2,
    _Float16* __restrict__ w1img, _Float16* __restrict__ w2img)
{
  int t = blockIdx.x * 256 + threadIdx.x;
  if (t < 128 * 72) {
    int r = t / 72, k = t - r * 72;
    w1img[t] = (k < 51) ? (_Float16)W1[r * 51 + k] : (_Float16)0.f;
  } else {
    int u = t - 128 * 72;
    if (u < 32 * 128) {
      int r = u >> 7, k = u & 127;
      w2img[u] = (r < 17) ? (_Float16)W2[r * 128 + k] : (_Float16)0.f;
    }
  }
}

// Update kernel: block = 64 pixels (one row segment) x 4 waves.
// Phase 1: sobel+rotation -> p_t[64][72] fp16 (K-major-contig per pixel)
// Phase 2: GEMM1 via MFMA: h = relu(W1 p + b1) -> h_t[64][136] fp16
// Phase 3: GEMM2 via MFMA: dx = W2 h + b2; epilogue adds fp32 state, masks.
__global__ __launch_bounds__(256, 3) void nca_update(
    const float* __restrict__ state, const float* __restrict__ rplane,
    const _Float16* __restrict__ w1img, const float* __restrict__ b1,
    const _Float16* __restrict__ w2img, const float* __restrict__ b2,
    float* __restrict__ outU, float* __restrict__ ch3plane)
{
  __shared__ _Float16 p_t[64][72];    // stride 144B: 16B-aligned, bank-balanced
  __shared__ _Float16 h_t[64][136];   // stride 272B: 16B-aligned, bank-balanced

  const int tid = threadIdx.x;
  const int lane = tid & 63;
  const int w = tid >> 6;        // wave 0..3
  const int l15 = lane & 15;
  const int g = lane >> 4;       // 0..3

  const int gpix0 = blockIdx.x * 64;
  const int b = gpix0 >> 14;
  const int ip0 = gpix0 & 16383;       // y*128 + x0 within plane
  const int y = ip0 >> 7;
  const int x0 = ip0 & 127;
  const float* sb = state + (size_t)b * Cn * HW;

  // --- W1/W2 fragments -> registers (global fp16 images, L2-hot) ---
  half8 a1[2][2];   // [mtile'][kc]  hidden rows 32w..32w+31
  half8 a2[2][4];   // [mtile][kc]   out channels 0..31
#pragma unroll
  for (int m = 0; m < 2; ++m)
#pragma unroll
    for (int kc = 0; kc < 2; ++kc) {
      int row = (2 * w + m) * 16 + l15;
      a1[m][kc] = *(const half8*)(w1img + row * 72 + kc * 32 + g * 8);
    }
#pragma unroll
  for (int m = 0; m < 2; ++m)
#pragma unroll
    for (int kc = 0; kc < 4; ++kc) {
      int row = m * 16 + l15;
      a2[m][kc] = *(const half8*)(w2img + row * 128 + kc * 32 + g * 8);
    }

  // --- Phase 1: sobel + rotation -> p_t (fp16) ---
  {
    int pix = tid & 63;
    int cg = tid >> 6;
    int x = x0 + pix;
    float ang = sb[16 * HW + ip0 + pix];
    float ca = cosf(ang), sa = sinf(ang);
    bool ym = y > 0, yp = y < Hn - 1, xm = x > 0, xp = x < Wn - 1;
    int r0 = (y - 1) * Wn + x, r1 = y * Wn + x, r2 = (y + 1) * Wn + x;
    for (int c = cg; c < Cn; c += 4) {
      const float* sc = sb + c * HW;
      float n00=0.f,n01=0.f,n02=0.f,n10=0.f,n11,n12=0.f,n20=0.f,n21=0.f,n22=0.f;
      if (ym) { if (xm) n00 = sc[r0-1]; n01 = sc[r0]; if (xp) n02 = sc[r0+1]; }
      if (xm) n10 = sc[r1-1];
      n11 = sc[r1];
      if (xp) n12 = sc[r1+1];
      if (yp) { if (xm) n20 = sc[r2-1]; n21 = sc[r2]; if (xp) n22 = sc[r2+1]; }
      float gx = (n02-n00 + 2.f*(n12-n10) + n22-n20) * 0.125f;
      float gy = (n20-n00 + 2.f*(n21-n01) + n22-n02) * 0.125f;
      p_t[pix][c]      = (_Float16)n11;
      p_t[pix][17 + c] = (_Float16)(ca * gx + sa * gy);
      p_t[pix][34 + c] = (_Float16)(ca * gy - sa * gx);
    }
    // zero K-pad 51..63 (phase 1 writes only 0..50; disjoint, no race)
    for (int k = 51 + cg; k < 64; k += 4) p_t[pix][k] = (_Float16)0.f;
  }
  __syncthreads();

  // --- Phase 2: GEMM1  h[128x64] = W1 p ---
  f32x4v acc1[2][4];
#pragma unroll
  for (int m = 0; m < 2; ++m)
#pragma unroll
    for (int nt = 0; nt < 4; ++nt) acc1[m][nt] = (f32x4v){0.f, 0.f, 0.f, 0.f};
#pragma unroll
  for (int kc = 0; kc < 2; ++kc) {
    half8 bf[4];
#pragma unroll
    for (int nt = 0; nt < 4; ++nt)
      bf[nt] = *(const half8*)(&p_t[nt * 16 + l15][kc * 32 + g * 8]);
#pragma unroll
    for (int m = 0; m < 2; ++m)
#pragma unroll
      for (int nt = 0; nt < 4; ++nt)
        acc1[m][nt] = __builtin_amdgcn_mfma_f32_16x16x32_f16(
            a1[m][kc], bf[nt], acc1[m][nt], 0, 0, 0);
  }
  // epilogue: bias + relu -> h_t fp16  (D layout: col=lane&15, row=(lane>>4)*4+i)
#pragma unroll
  for (int m = 0; m < 2; ++m) {
    int hid0 = (2 * w + m) * 16 + g * 4;
    f32x4v b1v = *(const f32x4v*)(b1 + hid0);
#pragma unroll
    for (int nt = 0; nt < 4; ++nt) {
      int pix = nt * 16 + l15;
      half4v hv;
#pragma unroll
      for (int i = 0; i < 4; ++i)
        hv[i] = (_Float16)fmaxf(acc1[m][nt][i] + b1v[i], 0.f);
      *(half4v*)(&h_t[pix][hid0]) = hv;
    }
  }
  __syncthreads();

  // --- Phase 3: GEMM2  dx[32x64] = W2 h ; wave w owns pixels w*16..w*16+15 ---
  f32x4v acc2[2] = {(f32x4v){0.f,0.f,0.f,0.f}, (f32x4v){0.f,0.f,0.f,0.f}};
#pragma unroll
  for (int kc = 0; kc < 4; ++kc) {
    half8 bf = *(const half8*)(&h_t[w * 16 + l15][kc * 32 + g * 8]);
    acc2[0] = __builtin_amdgcn_mfma_f32_16x16x32_f16(a2[0][kc], bf, acc2[0], 0, 0, 0);
    acc2[1] = __builtin_amdgcn_mfma_f32_16x16x32_f16(a2[1][kc], bf, acc2[1], 0, 0, 0);
  }
  // epilogue: dx + b2, fp32 state carry, update mask, store
  {
    int pixel = w * 16 + l15;
    int gp = gpix0 + pixel;
    float upd = (rplane[gp] < 0.5f) ? 1.f : 0.f;
    int ip = ip0 + pixel;
    f32x4v b2v = *(const f32x4v*)(b2 + g * 4);   // c = g*4+i for mt0
#pragma unroll
    for (int i = 0; i < 4; ++i) {
      int c = g * 4 + i;
      float s = sb[c * HW + ip];
      float nv = fmaf(acc2[0][i] + b2v[i], upd, s);
      outU[(size_t)b * Cn * HW + c * HW + ip] = nv;
      if (c == 3) ch3plane[gp] = nv;
    }
    if (g == 0) {  // mt1: only c=16 valid (i==0)
      float s = sb[16 * HW + ip];
      float nv = fmaf(acc2[1][0] + b2[16], upd, s);
      outU[(size_t)b * Cn * HW + 16 * HW + ip] = nv;
    }
  }
}

// Alive gating (unchanged): pre from old ch3, post from ws ch3 plane.
__global__ __launch_bounds__(256) void nca_alive(
    const float* __restrict__ oldState, const float* __restrict__ ch3plane,
    float* __restrict__ newState)
{
  int tid = blockIdx.x * blockDim.x + threadIdx.x;
  int x = tid & (Wn - 1);
  int y = (tid >> 7) & (Hn - 1);
  int b = tid >> 14;
  const float* o3 = oldState + ((size_t)b * Cn + 3) * HW;
  const float* p3 = ch3plane + (size_t)b * HW;
  float pre = -1e30f, post = -1e30f;
#pragma unroll
  for (int dy = -1; dy <= 1; ++dy) {
    int yy = y + dy;
    if (yy < 0 || yy >= Hn) continue;
#pragma unroll
    for (int dxx = -1; dxx <= 1; ++dxx) {
      int xx = x + dxx;
      if (xx < 0 || xx >= Wn) continue;
      pre = fmaxf(pre, o3[yy * Wn + xx]);
      post = fmaxf(post, p3[yy * Wn + xx]);
    }
  }
  float alive = (pre > 0.1f && post > 0.1f) ? 1.f : 0.f;
#pragma unroll
  for (int c = 0; c < Cn; ++c) {
    size_t i = (((size_t)b * Cn + c) * Hn + y) * Wn + x;
    newState[i] *= alive;
  }
}

__global__ __launch_bounds__(256) void nca_final(
    const float* __restrict__ last, float* __restrict__ out4)
{
  int tid = blockIdx.x * blockDim.x + threadIdx.x; // B*4*H*W
  int x = tid & 127, y = (tid >> 7) & 127, c = (tid >> 14) & 3, b = tid >> 16;
  out4[tid] = last[(((size_t)b * Cn + c) * Hn + y) * Wn + x];
}

extern "C" void kernel_launch(void* const* d_in, const int* in_sizes, int n_in,
                              void* d_out, int out_size, void* d_ws, size_t ws_size,
                              hipStream_t stream) {
  const float* init_state = (const float*)d_in[0];
  const float* rand_all   = (const float*)d_in[1];
  const float* W1 = (const float*)d_in[2];
  const float* b1 = (const float*)d_in[3];
  const float* W2 = (const float*)d_in[4];
  const float* b2 = (const float*)d_in[5];

  float* out = (float*)d_out;
  float* final4 = out;                                   // [B,4,H,W]
  float* dev_path = out + (size_t)Bn * 4 * HW;           // [STEPS,B,C,H,W]
  char* ws = (char*)d_ws;
  float* ch3 = (float*)(ws + CH3_OFF);
  _Float16* w1img = (_Float16*)(ws + W1IMG_OFF);
  _Float16* w2img = (_Float16*)(ws + W2IMG_OFF);

  const size_t stateSz = (size_t)Bn * Cn * HW;
  dim3 block(256);

  hipLaunchKernelGGL(nca_prep, dim3(52), block, 0, stream, W1, W2, w1img, w2img);

  for (int s = 0; s < STEPSn; ++s) {
    const float* cur = (s == 0) ? init_state
                                : (const float*)(dev_path + (size_t)(s - 1) * stateSz);
    float* nxt = dev_path + (size_t)s * stateSz;
    const float* rp = rand_all + (size_t)s * Bn * HW;
    hipLaunchKernelGGL(nca_update, dim3(NPIX / 64), block, 0, stream,
                       cur, rp, w1img, b1, w2img, b2, nxt, ch3);
    hipLaunchKernelGGL(nca_alive, dim3(NPIX / 256), block, 0, stream, cur, ch3, nxt);
  }
  hipLaunchKernelGGL(nca_final, dim3((size_t)Bn * 4 * HW / 256), block, 0,
                     stream, dev_path + (size_t)(STEPSn - 1) * stateSz, final4);
}